// Round 5
// baseline (138.326 us; speedup 1.0000x reference)
//
#include <hip/hip_runtime.h>
#include <hip/hip_bf16.h>

// Problem constants (fixed by setup_inputs): B=8, T=2048, D=1024, positions in [0,64).
#define NB 8
#define NT 2048
#define ND 1024
#define CAP 2048       // max tokens per bucket (worst case all T in one bucket)

// ---------------------------------------------------------------------------
// Workspace layout (byte offsets):
//   pad    : 64 floats of zeros                                          @ 0
//   G2f    : 128 floats  g2[k] = exp(-(k-63)^2/512), valid k in [0,126]  @ 256
//   cntv   : NB*64 int                                                   @ 768
//   cnth   : NB*64 int                                                   @ 2816
//   invden : NB*64*64 float  1/denominator for a token at (pv,ph)        @ 4864
//   tokv   : NB*64*CAP int   packed (t | posh[t]<<16), bucketed by posv  @ 135936
//   tokh   : NB*64*CAP int   packed (t | posv[t]<<16), bucketed by posh  @ 4330240
//   B1     : NB*64*64*1024 float   [b][q=ph'][pv][d]                     @ 8524544
// ---------------------------------------------------------------------------
#define OFF_G2     256
#define OFF_CNTV   768
#define OFF_CNTH   2816
#define OFF_INVDEN 4864
#define OFF_TOKV   135936
#define OFF_TOKH   4330240
#define OFF_B1     8524544
#define B1_SLAB    ((size_t)64 * 64 * 1024 * 4)   // bytes per batch slab (16 MB)

// K1: deterministic CSR bucket lists via wave ballot compaction (no atomics).
// Entries are packed: t | (other_axis_pos[t] << 16) — so k2/k3 need ONE
// uniform load per token (kills the LDS staging + syncs that made k2
// prologue-bound). Block 0 fills the g table (64-float zero pad below it).
__global__ __launch_bounds__(256) void k1_bucket(
    const int* __restrict__ posv, const int* __restrict__ posh,
    int* __restrict__ tokv, int* __restrict__ tokh,
    int* __restrict__ cntv, int* __restrict__ cnth,
    float* __restrict__ gbase)   // = ws base; table lives at gbase+64
{
    int b    = blockIdx.x >> 5;      // NB*32 blocks
    int blk  = blockIdx.x & 31;
    int wave = threadIdx.x >> 6;
    int lane = threadIdx.x & 63;

    if (blockIdx.x == 0 && threadIdx.x < 192) {
        int k = (int)threadIdx.x - 64;     // table index; <0 = pad
        float v = 0.0f;
        if (k >= 0 && k < 127) {
            int r = k - 63;
            v = expf(-(float)(r * r) * (1.0f / 512.0f));
        }
        gbase[threadIdx.x] = v;
    }

    int task   = blk * 4 + wave;                // 0..127
    int bucket = task & 63;
    int use_ph = task >> 6;
    const int* pos  = use_ph ? posh : posv;
    const int* opos = use_ph ? posv : posh;
    int* tok = (use_ph ? tokh : tokv) + ((size_t)(b * 64 + bucket)) * CAP;
    int* cnt = use_ph ? cnth : cntv;

    int vals[32];
#pragma unroll
    for (int k = 0; k < 32; k++) vals[k] = pos[b * NT + k * 64 + lane];

    unsigned long long lmask = (1ull << lane) - 1ull;
    int cursor = 0;
#pragma unroll 4
    for (int k = 0; k < 32; k++) {
        bool hit = (vals[k] == bucket);
        unsigned long long m = __ballot(hit);
        if (hit) {
            int t = k * 64 + lane;
            tok[cursor + __popcll(m & lmask)] = t | (opos[b * NT + t] << 16);
        }
        cursor += (int)__popcll(m);
    }
    if (lane == 0) cnt[b * 64 + bucket] = cursor;
}

// KDEN: denominator table. den[pv][ph] = sum_{j,k} hist[j][k] g(pv-j) g(ph-k).
// Integer LDS-atomic histogram (deterministic), then two 64x64 mini-matmuls.
__global__ __launch_bounds__(256) void kden(
    const int* __restrict__ posv, const int* __restrict__ posh,
    const float* __restrict__ G2f, float* __restrict__ invden, int b0)
{
    int b   = b0 + (blockIdx.x >> 3);
    int phg = blockIdx.x & 7;
    int tid = threadIdx.x;

    __shared__ int   hist[64][64];
    __shared__ float g2s[128];
    __shared__ float tmp[64][8];

#pragma unroll
    for (int k = 0; k < 16; k++) ((int*)hist)[tid + (k << 8)] = 0;
    if (tid < 128) g2s[tid] = G2f[tid];
    __syncthreads();
#pragma unroll
    for (int k = 0; k < 8; k++) {
        int t = (k << 8) + tid;
        atomicAdd(&hist[posv[b * NT + t]][posh[b * NT + t]], 1);
    }
    __syncthreads();
#pragma unroll
    for (int c = 0; c < 2; c++) {
        int cell = (c << 8) + tid;        // 512 cells: 64 j x 8 phl
        int j    = cell >> 3;
        int phl  = cell & 7;
        int ph   = (phg << 3) + phl;
        float s = 0.f;
        for (int k = 0; k < 64; k++)
            s += (float)hist[j][k] * g2s[63 + k - ph];
        tmp[j][phl] = s;
    }
    __syncthreads();
#pragma unroll
    for (int c = 0; c < 2; c++) {
        int cell = (c << 8) + tid;
        int pv   = cell >> 3;
        int phl  = cell & 7;
        int ph   = (phg << 3) + phl;
        float s = 0.f;
        for (int j = 0; j < 64; j++)
            s += g2s[63 + j - pv] * tmp[j][phl];
        invden[(b * 64 + pv) * 64 + ph] = 1.0f / s;
    }
}

// K2: h-conv from packed token lists.
//   B1[b][q][pv][d] = sum_{t: posv_t==pv} g(q - posh_t) * x[b][t][d]
// Block = (b, dc, pv-group of 4); wave w owns q-tile [16w,16w+16); lane owns
// d. No LDS, no __syncthreads: per token = 1 uniform packed load + 1
// coalesced x load + 1 scalar g-window (s_load_dwordx16) + 16 FMA.
__global__ __launch_bounds__(256) void k2_convh(
    const float* __restrict__ x,
    const int* __restrict__ tokv, const int* __restrict__ cntv,
    const float* __restrict__ G2f, float* __restrict__ B1, int b0)
{
    int pv0  = (blockIdx.x & 15) << 2;
    int dc   = (blockIdx.x >> 4) & 15;
    int b    = b0 + (blockIdx.x >> 8);
    int tid  = threadIdx.x;
    int lane = tid & 63;
    int goff = __builtin_amdgcn_readfirstlane(63 + ((tid >> 6) << 4));  // 63+16w
    int wq   = goff - 63;                                               // 16w
    int d0   = dc << 6;

    const float* xb = x + (((size_t)b * NT) << 10) + d0 + lane;

    for (int pvi = 0; pvi < 4; ++pvi) {
        int pv = pv0 + pvi;
        int n  = cntv[b * 64 + pv];
        const int* toks = tokv + ((size_t)(b * 64 + pv)) * CAP;

        float acc[16];
#pragma unroll
        for (int q = 0; q < 16; q++) acc[q] = 0.f;

        int i = 0;
        for (; i + 4 <= n; i += 4) {
            float xv[4]; const float* gp[4];
#pragma unroll
            for (int j = 0; j < 4; j++) {
                int pk = __builtin_amdgcn_readfirstlane(toks[i + j]);
                int t  = pk & 0xffff;
                int ph = pk >> 16;
                xv[j] = xb[(size_t)t << 10];
                gp[j] = G2f + (goff - ph);     // fully scalar address
            }
#pragma unroll
            for (int q = 0; q < 16; q++) {
                float a = acc[q];
#pragma unroll
                for (int j = 0; j < 4; j++)
                    a = fmaf(gp[j][q], xv[j], a);
                acc[q] = a;
            }
        }
        for (; i < n; i++) {
            int pk = __builtin_amdgcn_readfirstlane(toks[i]);
            int t  = pk & 0xffff;
            int ph = pk >> 16;
            float xv = xb[(size_t)t << 10];
            const float* gp = G2f + (goff - ph);
#pragma unroll
            for (int q = 0; q < 16; q++)
                acc[q] = fmaf(gp[q], xv, acc[q]);
        }

        // B1[b][q][pv][d], q = wq + qi
        float* B1p = B1 + (((size_t)(b - b0)) << 22) + (((size_t)wq) << 16)
                   + (((size_t)pv) << 10) + d0 + lane;
#pragma unroll
        for (int q = 0; q < 16; q++)
            B1p[(size_t)q << 16] = acc[q];
    }
}

// K3: dense v-conv fused with token gather + normalization (round-3
// structure — it was at the FMA floor — with scalarized g pointer).
// Stage u[j][d] = B1[b][ph][j][d] (contiguous 64KB span) into LDS;
// y[pv'][d] = sum_j g(pv'-j) u[j][d]; reuse u's LDS for y; scatter
// out[t][d] = y[pv_t][d] * invden[pv_t][ph] via packed token list.
__global__ __launch_bounds__(256) void k3_convv(
    const int* __restrict__ tokh, const int* __restrict__ cnth,
    const float* __restrict__ G2f, const float* __restrict__ B1,
    const float* __restrict__ invden, float* __restrict__ out, int b0)
{
    int ph   = blockIdx.x & 63;
    int dc   = (blockIdx.x >> 6) & 15;
    int b    = b0 + (blockIdx.x >> 10);
    int tid  = threadIdx.x;
    int lane = tid & 63;
    int w    = tid >> 6;
    int wq   = __builtin_amdgcn_readfirstlane((tid >> 6) << 4);   // 16w
    int d0   = dc << 6;

    int n = cnth[b * 64 + ph];
    if (n == 0) return;               // uniform across block: safe

    __shared__ float u[64][64];       // staged B1 column; reused as y

    const float* B1p = B1 + (((size_t)(b - b0)) << 22) + (((size_t)ph) << 16)
                     + d0 + lane;
#pragma unroll
    for (int k = 0; k < 16; k++) {
        int j = (k << 2) + w;
        u[j][lane] = B1p[(size_t)j << 10];
    }
    __syncthreads();

    float acc[16];
#pragma unroll
    for (int q = 0; q < 16; q++) acc[q] = 0.f;
    const float* gq = G2f + 63 + wq;
#pragma unroll
    for (int j = 0; j < 64; j += 4) {
        float uv[4];
#pragma unroll
        for (int jj = 0; jj < 4; jj++) uv[jj] = u[j + jj][lane];
#pragma unroll
        for (int q = 0; q < 16; q++) {
            float a = acc[q];
#pragma unroll
            for (int jj = 0; jj < 4; jj++)
                a = fmaf(gq[q - (j + jj)], uv[jj], a);
            acc[q] = a;
        }
    }
    __syncthreads();                   // all u reads complete
#pragma unroll
    for (int q = 0; q < 16; q++) u[wq + q][lane] = acc[q];   // y into u's LDS
    __syncthreads();

    const int* toks = tokh + ((size_t)(b * 64 + ph)) * CAP;
    float* outb = out + (((size_t)b * NT) << 10) + d0 + lane;
    const float* ivb = invden + ((b * 64) << 6) + ph;

    for (int i = w; i < n; i += 4) {
        int pk = __builtin_amdgcn_readfirstlane(toks[i]);
        int t  = pk & 0xffff;
        int pv = pk >> 16;
        float iv = ivb[pv << 6];       // uniform s_load
        outb[(size_t)t << 10] = u[pv][lane] * iv;
    }
}

// Safety-net fallback (no workspace needed): direct O(T^2 * D) attention.
__global__ __launch_bounds__(256) void k_naive(
    const float* __restrict__ x, const int* __restrict__ posv,
    const int* __restrict__ posh, float* __restrict__ out)
{
    int t   = blockIdx.x & (NT - 1);
    int b   = blockIdx.x >> 11;
    int tid = threadIdx.x;

    __shared__ float s_w[NT];
    __shared__ float s_red[256];

    int pvt = posv[b * NT + t];
    int pht = posh[b * NT + t];

    float dsum = 0.0f;
    for (int s = tid; s < NT; s += 256) {
        int dv = pvt - posv[b * NT + s];
        int dh = pht - posh[b * NT + s];
        float w = expf(-(float)(dv * dv + dh * dh) * (1.0f / 512.0f));
        s_w[s] = w;
        dsum += w;
    }
    s_red[tid] = dsum;
    __syncthreads();
    for (int off = 128; off > 0; off >>= 1) {
        if (tid < off) s_red[tid] += s_red[tid + off];
        __syncthreads();
    }
    float inv = 1.0f / s_red[0];

    float a0 = 0.f, a1 = 0.f, a2 = 0.f, a3 = 0.f;
    for (int s = 0; s < NT; s++) {
        float w = s_w[s];
        const float* xr = x + (((size_t)(b * NT + s)) << 10);
        a0 = fmaf(w, xr[tid + 0],   a0);
        a1 = fmaf(w, xr[tid + 256], a1);
        a2 = fmaf(w, xr[tid + 512], a2);
        a3 = fmaf(w, xr[tid + 768], a3);
    }
    size_t ob = (((size_t)(b * NT + t)) << 10) + tid;
    out[ob + 0]   = a0 * inv;
    out[ob + 256] = a1 * inv;
    out[ob + 512] = a2 * inv;
    out[ob + 768] = a3 * inv;
}

extern "C" void kernel_launch(void* const* d_in, const int* in_sizes, int n_in,
                              void* d_out, int out_size, void* d_ws, size_t ws_size,
                              hipStream_t stream) {
    const float* x    = (const float*)d_in[0];
    const int*   posv = (const int*)d_in[1];
    const int*   posh = (const int*)d_in[2];
    float*       out  = (float*)d_out;

    char* ws = (char*)d_ws;
    float* gbase  = (float*)ws;               // pad + table
    float* G2f    = (float*)(ws + OFF_G2);
    int*   cntv   = (int*)(ws + OFF_CNTV);
    int*   cnth   = (int*)(ws + OFF_CNTH);
    float* invden = (float*)(ws + OFF_INVDEN);
    int*   tokv   = (int*)(ws + OFF_TOKV);
    int*   tokh   = (int*)(ws + OFF_TOKH);
    float* B1     = (float*)(ws + OFF_B1);

    const size_t needFull = (size_t)OFF_B1 + (size_t)NB * B1_SLAB;   // ~143 MB
    const size_t needLoop = (size_t)OFF_B1 + B1_SLAB;                // ~25 MB

    if (ws_size >= needFull) {
        k1_bucket<<<NB * 32, 256, 0, stream>>>(posv, posh, tokv, tokh, cntv, cnth, gbase);
        kden<<<NB * 8, 256, 0, stream>>>(posv, posh, G2f, invden, 0);
        k2_convh<<<NB * 256, 256, 0, stream>>>(x, tokv, cntv, G2f, B1, 0);
        k3_convv<<<NB * 1024, 256, 0, stream>>>(tokh, cnth, G2f, B1, invden, out, 0);
    } else if (ws_size >= needLoop) {
        k1_bucket<<<NB * 32, 256, 0, stream>>>(posv, posh, tokv, tokh, cntv, cnth, gbase);
        for (int b = 0; b < NB; b++) {
            kden<<<8, 256, 0, stream>>>(posv, posh, G2f, invden, b);
            k2_convh<<<256, 256, 0, stream>>>(x, tokv, cntv, G2f, B1, b);
            k3_convv<<<1024, 256, 0, stream>>>(tokh, cnth, G2f, B1, invden, out, b);
        }
    } else {
        k_naive<<<NB * NT, 256, 0, stream>>>(x, posv, posh, out);
    }
}

// Round 6
// 119.274 us; speedup vs baseline: 1.1597x; 1.1597x over previous
//
#include <hip/hip_runtime.h>
#include <hip/hip_bf16.h>

// Problem constants (fixed by setup_inputs): B=8, T=2048, D=1024, positions in [0,64).
#define NB 8
#define NT 2048
#define ND 1024
#define CAP 2048       // max tokens per bucket (worst case all T in one bucket)

typedef unsigned short ushort_t;

// bf16 helpers: store with RNE rounding (intrinsic), load via exact bit shift.
__device__ __forceinline__ ushort_t f2bf(float f) {
    __hip_bfloat16 h = __float2bfloat16(f);
    return *reinterpret_cast<ushort_t*>(&h);
}
__device__ __forceinline__ float bf2f(ushort_t u) {
    unsigned int v = ((unsigned int)u) << 16;
    return __int_as_float((int)v);
}

// ---------------------------------------------------------------------------
// Workspace layout (byte offsets):
//   pad    : 64 floats of zeros                                          @ 0
//   G2f    : 128 floats  g2[k] = exp(-(k-63)^2/512), valid k in [0,126]  @ 256
//   cntv   : NB*64 int                                                   @ 768
//   cnth   : NB*64 int                                                   @ 2816
//   invden : NB*64*64 float  1/denominator for a token at (pv,ph)        @ 4864
//   tokv   : NB*64*CAP int   packed (t | posh[t]<<16), bucketed by posv  @ 135936
//   tokh   : NB*64*CAP int   packed (t | posv[t]<<16), bucketed by posh  @ 4330240
//   B1     : NB*64*64*1024 bf16   [b][q=ph'][pv][d]                      @ 8524544
// ---------------------------------------------------------------------------
#define OFF_G2     256
#define OFF_CNTV   768
#define OFF_CNTH   2816
#define OFF_INVDEN 4864
#define OFF_TOKV   135936
#define OFF_TOKH   4330240
#define OFF_B1     8524544
#define B1_SLAB    ((size_t)64 * 64 * 1024 * 2)   // bytes per batch slab (8 MB, bf16)

// K1: deterministic CSR bucket lists via wave ballot compaction (no atomics).
// Entries packed: t | (other_axis_pos[t] << 16). Block 0 fills the g table.
__global__ __launch_bounds__(256) void k1_bucket(
    const int* __restrict__ posv, const int* __restrict__ posh,
    int* __restrict__ tokv, int* __restrict__ tokh,
    int* __restrict__ cntv, int* __restrict__ cnth,
    float* __restrict__ gbase)   // = ws base; table lives at gbase+64
{
    int b    = blockIdx.x >> 5;      // NB*32 blocks
    int blk  = blockIdx.x & 31;
    int wave = threadIdx.x >> 6;
    int lane = threadIdx.x & 63;

    if (blockIdx.x == 0 && threadIdx.x < 192) {
        int k = (int)threadIdx.x - 64;     // table index; <0 = pad
        float v = 0.0f;
        if (k >= 0 && k < 127) {
            int r = k - 63;
            v = expf(-(float)(r * r) * (1.0f / 512.0f));
        }
        gbase[threadIdx.x] = v;
    }

    int task   = blk * 4 + wave;                // 0..127
    int bucket = task & 63;
    int use_ph = task >> 6;
    const int* pos  = use_ph ? posh : posv;
    const int* opos = use_ph ? posv : posh;
    int* tok = (use_ph ? tokh : tokv) + ((size_t)(b * 64 + bucket)) * CAP;
    int* cnt = use_ph ? cnth : cntv;

    int vals[32];
#pragma unroll
    for (int k = 0; k < 32; k++) vals[k] = pos[b * NT + k * 64 + lane];

    unsigned long long lmask = (1ull << lane) - 1ull;
    int cursor = 0;
#pragma unroll 4
    for (int k = 0; k < 32; k++) {
        bool hit = (vals[k] == bucket);
        unsigned long long m = __ballot(hit);
        if (hit) {
            int t = k * 64 + lane;
            tok[cursor + __popcll(m & lmask)] = t | (opos[b * NT + t] << 16);
        }
        cursor += (int)__popcll(m);
    }
    if (lane == 0) cnt[b * 64 + bucket] = cursor;
}

// KDEN: denominator table. den[pv][ph] = sum_{j,k} hist[j][k] g(pv-j) g(ph-k).
// Integer LDS-atomic histogram (deterministic), then two 64x64 mini-matmuls.
__global__ __launch_bounds__(256) void kden(
    const int* __restrict__ posv, const int* __restrict__ posh,
    const float* __restrict__ G2f, float* __restrict__ invden, int b0)
{
    int b   = b0 + (blockIdx.x >> 3);
    int phg = blockIdx.x & 7;
    int tid = threadIdx.x;

    __shared__ int   hist[64][64];
    __shared__ float g2s[128];
    __shared__ float tmp[64][8];

#pragma unroll
    for (int k = 0; k < 16; k++) ((int*)hist)[tid + (k << 8)] = 0;
    if (tid < 128) g2s[tid] = G2f[tid];
    __syncthreads();
#pragma unroll
    for (int k = 0; k < 8; k++) {
        int t = (k << 8) + tid;
        atomicAdd(&hist[posv[b * NT + t]][posh[b * NT + t]], 1);
    }
    __syncthreads();
#pragma unroll
    for (int c = 0; c < 2; c++) {
        int cell = (c << 8) + tid;        // 512 cells: 64 j x 8 phl
        int j    = cell >> 3;
        int phl  = cell & 7;
        int ph   = (phg << 3) + phl;
        float s = 0.f;
        for (int k = 0; k < 64; k++)
            s += (float)hist[j][k] * g2s[63 + k - ph];
        tmp[j][phl] = s;
    }
    __syncthreads();
#pragma unroll
    for (int c = 0; c < 2; c++) {
        int cell = (c << 8) + tid;
        int pv   = cell >> 3;
        int phl  = cell & 7;
        int ph   = (phg << 3) + phl;
        float s = 0.f;
        for (int j = 0; j < 64; j++)
            s += g2s[63 + j - pv] * tmp[j][phl];
        invden[(b * 64 + pv) * 64 + ph] = 1.0f / s;
    }
}

// K2: h-conv from packed token lists.
//   B1[b][q][pv][d] = sum_{t: posv_t==pv} g(q - posh_t) * x[b][t][d]   (bf16 out)
// Block = (b, dc, pv-group of 4); wave w owns q-tile [16w,16w+16); lane owns d.
// Per token: 1 s_load (packed tok) + 1 coalesced x VMEM + 1 scalar 16-float
// g-window (s_load, correct choice here: 16 FRESH values per token) + 16 FMA.
// 8-deep token unroll keeps 8 x-loads in flight per wave.
__global__ __launch_bounds__(256) void k2_convh(
    const float* __restrict__ x,
    const int* __restrict__ tokv, const int* __restrict__ cntv,
    const float* __restrict__ G2f, ushort_t* __restrict__ B1, int b0)
{
    int pv0  = (blockIdx.x & 15) << 2;
    int dc   = (blockIdx.x >> 4) & 15;
    int b    = b0 + (blockIdx.x >> 8);
    int tid  = threadIdx.x;
    int lane = tid & 63;
    int goff = __builtin_amdgcn_readfirstlane(63 + ((tid >> 6) << 4));  // 63+16w
    int wq   = goff - 63;                                               // 16w
    int d0   = dc << 6;

    const float* xb = x + (((size_t)b * NT) << 10) + d0 + lane;

    for (int pvi = 0; pvi < 4; ++pvi) {
        int pv = pv0 + pvi;
        int n  = cntv[b * 64 + pv];
        const int* toks = tokv + ((size_t)(b * 64 + pv)) * CAP;

        float acc[16];
#pragma unroll
        for (int q = 0; q < 16; q++) acc[q] = 0.f;

        int i = 0;
        for (; i + 8 <= n; i += 8) {
            float xv[8]; const float* gp[8];
#pragma unroll
            for (int j = 0; j < 8; j++) {
                int pk = __builtin_amdgcn_readfirstlane(toks[i + j]);
                int t  = pk & 0xffff;
                int ph = pk >> 16;
                xv[j] = xb[(size_t)t << 10];
                gp[j] = G2f + (goff - ph);     // fully scalar address
            }
#pragma unroll
            for (int q = 0; q < 16; q++) {
                float a = acc[q];
#pragma unroll
                for (int j = 0; j < 8; j++)
                    a = fmaf(gp[j][q], xv[j], a);
                acc[q] = a;
            }
        }
        for (; i < n; i++) {
            int pk = __builtin_amdgcn_readfirstlane(toks[i]);
            int t  = pk & 0xffff;
            int ph = pk >> 16;
            float xv = xb[(size_t)t << 10];
            const float* gp = G2f + (goff - ph);
#pragma unroll
            for (int q = 0; q < 16; q++)
                acc[q] = fmaf(gp[q], xv, acc[q]);
        }

        // B1[b][q][pv][d] (bf16), q = wq + qi
        ushort_t* B1p = B1 + (((size_t)(b - b0)) << 22) + (((size_t)wq) << 16)
                      + (((size_t)pv) << 10) + d0 + lane;
#pragma unroll
        for (int q = 0; q < 16; q++)
            B1p[(size_t)q << 16] = f2bf(acc[q]);
    }
}

// K3: dense v-conv fused with token gather + normalization.
// ROUND-3 REGISTER PATTERN RESTORED: g window lives in VGPRs — per-lane
// loads (NOT readfirstlane'd: scalarizing pushed 79 values into a 64-SGPR
// budget -> in-loop s_load remat = the round-5 regression). Fully unrolled
// j-loop keeps all gv[] indices compile-time (no scratch).
// Stage u[j][d] = bf16 B1[b][ph][j][d] -> fp32 LDS; y = G*u; reuse u for y;
// scatter out[t][d] = y[pv_t][d] * invden[pv_t][ph] via packed token list.
__global__ __launch_bounds__(256) void k3_convv(
    const int* __restrict__ tokh, const int* __restrict__ cnth,
    const float* __restrict__ G2f, const ushort_t* __restrict__ B1,
    const float* __restrict__ invden, float* __restrict__ out, int b0)
{
    int ph   = blockIdx.x & 63;
    int dc   = (blockIdx.x >> 6) & 15;
    int b    = b0 + (blockIdx.x >> 10);
    int tid  = threadIdx.x;
    int lane = tid & 63;
    int w    = tid >> 6;
    int wq   = w << 4;                 // per-lane on purpose (VGPR g loads)
    int d0   = dc << 6;

    int n = cnth[b * 64 + ph];
    if (n == 0) return;               // uniform across block: safe

    __shared__ float u[64][64];       // staged B1 column; reused as y

    const ushort_t* B1p = B1 + (((size_t)(b - b0)) << 22) + (((size_t)ph) << 16)
                        + d0 + lane;
#pragma unroll
    for (int k = 0; k < 16; k++) {
        int j = (k << 2) + w;
        u[j][lane] = bf2f(B1p[(size_t)j << 10]);
    }

    // hoist the whole g window into VGPRs: conv needs g(wq+q-j) = G2f[wq+63+q-j],
    // (q,j) in [0,16)x[0,64) -> indices G2f[wq .. wq+78]
    float gv[79];
#pragma unroll
    for (int k = 0; k < 79; k++) gv[k] = G2f[wq + k];

    float acc[16];
#pragma unroll
    for (int q = 0; q < 16; q++) acc[q] = 0.f;

    __syncthreads();

#pragma unroll
    for (int j = 0; j < 64; j += 4) {
        float uv[4];
#pragma unroll
        for (int jj = 0; jj < 4; jj++) uv[jj] = u[j + jj][lane];
#pragma unroll
        for (int q = 0; q < 16; q++) {
            float a = acc[q];
#pragma unroll
            for (int jj = 0; jj < 4; jj++)
                a = fmaf(gv[63 + q - (j + jj)], uv[jj], a);
            acc[q] = a;
        }
    }
    __syncthreads();                   // all u reads complete
#pragma unroll
    for (int q = 0; q < 16; q++) u[wq + q][lane] = acc[q];   // y into u's LDS
    __syncthreads();

    const int* toks = tokh + ((size_t)(b * 64 + ph)) * CAP;
    float* outb = out + (((size_t)b * NT) << 10) + d0 + lane;
    const float* ivb = invden + ((b * 64) << 6) + ph;

    for (int i = w; i < n; i += 4) {
        int pk = __builtin_amdgcn_readfirstlane(toks[i]);
        int t  = pk & 0xffff;
        int pv = pk >> 16;
        float iv = ivb[pv << 6];       // uniform s_load
        outb[(size_t)t << 10] = u[pv][lane] * iv;
    }
}

// Safety-net fallback (no workspace needed): direct O(T^2 * D) attention.
__global__ __launch_bounds__(256) void k_naive(
    const float* __restrict__ x, const int* __restrict__ posv,
    const int* __restrict__ posh, float* __restrict__ out)
{
    int t   = blockIdx.x & (NT - 1);
    int b   = blockIdx.x >> 11;
    int tid = threadIdx.x;

    __shared__ float s_w[NT];
    __shared__ float s_red[256];

    int pvt = posv[b * NT + t];
    int pht = posh[b * NT + t];

    float dsum = 0.0f;
    for (int s = tid; s < NT; s += 256) {
        int dv = pvt - posv[b * NT + s];
        int dh = pht - posh[b * NT + s];
        float w = expf(-(float)(dv * dv + dh * dh) * (1.0f / 512.0f));
        s_w[s] = w;
        dsum += w;
    }
    s_red[tid] = dsum;
    __syncthreads();
    for (int off = 128; off > 0; off >>= 1) {
        if (tid < off) s_red[tid] += s_red[tid + off];
        __syncthreads();
    }
    float inv = 1.0f / s_red[0];

    float a0 = 0.f, a1 = 0.f, a2 = 0.f, a3 = 0.f;
    for (int s = 0; s < NT; s++) {
        float w = s_w[s];
        const float* xr = x + (((size_t)(b * NT + s)) << 10);
        a0 = fmaf(w, xr[tid + 0],   a0);
        a1 = fmaf(w, xr[tid + 256], a1);
        a2 = fmaf(w, xr[tid + 512], a2);
        a3 = fmaf(w, xr[tid + 768], a3);
    }
    size_t ob = (((size_t)(b * NT + t)) << 10) + tid;
    out[ob + 0]   = a0 * inv;
    out[ob + 256] = a1 * inv;
    out[ob + 512] = a2 * inv;
    out[ob + 768] = a3 * inv;
}

extern "C" void kernel_launch(void* const* d_in, const int* in_sizes, int n_in,
                              void* d_out, int out_size, void* d_ws, size_t ws_size,
                              hipStream_t stream) {
    const float* x    = (const float*)d_in[0];
    const int*   posv = (const int*)d_in[1];
    const int*   posh = (const int*)d_in[2];
    float*       out  = (float*)d_out;

    char* ws = (char*)d_ws;
    float*    gbase  = (float*)ws;               // pad + table
    float*    G2f    = (float*)(ws + OFF_G2);
    int*      cntv   = (int*)(ws + OFF_CNTV);
    int*      cnth   = (int*)(ws + OFF_CNTH);
    float*    invden = (float*)(ws + OFF_INVDEN);
    int*      tokv   = (int*)(ws + OFF_TOKV);
    int*      tokh   = (int*)(ws + OFF_TOKH);
    ushort_t* B1     = (ushort_t*)(ws + OFF_B1);

    const size_t needFull = (size_t)OFF_B1 + (size_t)NB * B1_SLAB;   // ~73 MB
    const size_t needLoop = (size_t)OFF_B1 + B1_SLAB;                // ~17 MB

    if (ws_size >= needFull) {
        k1_bucket<<<NB * 32, 256, 0, stream>>>(posv, posh, tokv, tokh, cntv, cnth, gbase);
        kden<<<NB * 8, 256, 0, stream>>>(posv, posh, G2f, invden, 0);
        k2_convh<<<NB * 256, 256, 0, stream>>>(x, tokv, cntv, G2f, B1, 0);
        k3_convv<<<NB * 1024, 256, 0, stream>>>(tokh, cnth, G2f, B1, invden, out, 0);
    } else if (ws_size >= needLoop) {
        k1_bucket<<<NB * 32, 256, 0, stream>>>(posv, posh, tokv, tokh, cntv, cnth, gbase);
        for (int b = 0; b < NB; b++) {
            kden<<<8, 256, 0, stream>>>(posv, posh, G2f, invden, b);
            k2_convh<<<256, 256, 0, stream>>>(x, tokv, cntv, G2f, B1, b);
            k3_convv<<<1024, 256, 0, stream>>>(tokh, cnth, G2f, B1, invden, out, b);
        }
    } else {
        k_naive<<<NB * NT, 256, 0, stream>>>(x, posv, posh, out);
    }
}

// Round 7
// 118.742 us; speedup vs baseline: 1.1649x; 1.0045x over previous
//
#include <hip/hip_runtime.h>
#include <hip/hip_bf16.h>

// Problem constants (fixed by setup_inputs): B=8, T=2048, D=1024, positions in [0,64).
#define NB 8
#define NT 2048
#define ND 1024
#define CAP 2048       // max tokens per bucket (worst case all T in one bucket)

typedef unsigned short ushort_t;

// bf16 helpers: store with RNE rounding (intrinsic), load via exact bit shift.
__device__ __forceinline__ ushort_t f2bf(float f) {
    __hip_bfloat16 h = __float2bfloat16(f);
    return *reinterpret_cast<ushort_t*>(&h);
}
__device__ __forceinline__ float bf2f(ushort_t u) {
    unsigned int v = ((unsigned int)u) << 16;
    return __int_as_float((int)v);
}

// ---------------------------------------------------------------------------
// Workspace layout (byte offsets):
//   pad    : 64 floats of zeros                                          @ 0
//   G2f    : 128 floats  g2[k] = exp(-(k-63)^2/512), valid k in [0,126]  @ 256
//   cntv   : NB*64 int                                                   @ 768
//   cnth   : NB*64 int                                                   @ 2816
//   invden : NB*64*64 float  1/denominator for a token at (pv,ph)        @ 4864
//   tokv   : NB*64*CAP int   packed (t | posh[t]<<16), bucketed by posv  @ 135936
//   tokh   : NB*64*CAP int   packed (t | posv[t]<<16), bucketed by posh  @ 4330240
//   B1     : NB*64*64*1024 bf16   [b][q=ph'][pv][d]                      @ 8524544
// ---------------------------------------------------------------------------
#define OFF_G2     256
#define OFF_CNTV   768
#define OFF_CNTH   2816
#define OFF_INVDEN 4864
#define OFF_TOKV   135936
#define OFF_TOKH   4330240
#define OFF_B1     8524544
#define B1_SLAB    ((size_t)64 * 64 * 1024 * 2)   // bytes per batch slab (8 MB, bf16)

// K1: deterministic CSR bucket lists via wave ballot compaction (no atomics).
// Entries packed: t | (other_axis_pos[t] << 16). Block 0 fills the g table.
__global__ __launch_bounds__(256) void k1_bucket(
    const int* __restrict__ posv, const int* __restrict__ posh,
    int* __restrict__ tokv, int* __restrict__ tokh,
    int* __restrict__ cntv, int* __restrict__ cnth,
    float* __restrict__ gbase)   // = ws base; table lives at gbase+64
{
    int b    = blockIdx.x >> 5;      // NB*32 blocks
    int blk  = blockIdx.x & 31;
    int wave = threadIdx.x >> 6;
    int lane = threadIdx.x & 63;

    if (blockIdx.x == 0 && threadIdx.x < 192) {
        int k = (int)threadIdx.x - 64;     // table index; <0 = pad
        float v = 0.0f;
        if (k >= 0 && k < 127) {
            int r = k - 63;
            v = expf(-(float)(r * r) * (1.0f / 512.0f));
        }
        gbase[threadIdx.x] = v;
    }

    int task   = blk * 4 + wave;                // 0..127
    int bucket = task & 63;
    int use_ph = task >> 6;
    const int* pos  = use_ph ? posh : posv;
    const int* opos = use_ph ? posv : posh;
    int* tok = (use_ph ? tokh : tokv) + ((size_t)(b * 64 + bucket)) * CAP;
    int* cnt = use_ph ? cnth : cntv;

    int vals[32];
#pragma unroll
    for (int k = 0; k < 32; k++) vals[k] = pos[b * NT + k * 64 + lane];

    unsigned long long lmask = (1ull << lane) - 1ull;
    int cursor = 0;
#pragma unroll 4
    for (int k = 0; k < 32; k++) {
        bool hit = (vals[k] == bucket);
        unsigned long long m = __ballot(hit);
        if (hit) {
            int t = k * 64 + lane;
            tok[cursor + __popcll(m & lmask)] = t | (opos[b * NT + t] << 16);
        }
        cursor += (int)__popcll(m);
    }
    if (lane == 0) cnt[b * 64 + bucket] = cursor;
}

// KDEN: denominator table. den[pv][ph] = sum_{j,k} hist[j][k] g(pv-j) g(ph-k).
// Integer LDS-atomic histogram (deterministic), then two 64x64 mini-matmuls.
__global__ __launch_bounds__(256) void kden(
    const int* __restrict__ posv, const int* __restrict__ posh,
    const float* __restrict__ G2f, float* __restrict__ invden, int b0)
{
    int b   = b0 + (blockIdx.x >> 3);
    int phg = blockIdx.x & 7;
    int tid = threadIdx.x;

    __shared__ int   hist[64][64];
    __shared__ float g2s[128];
    __shared__ float tmp[64][8];

#pragma unroll
    for (int k = 0; k < 16; k++) ((int*)hist)[tid + (k << 8)] = 0;
    if (tid < 128) g2s[tid] = G2f[tid];
    __syncthreads();
#pragma unroll
    for (int k = 0; k < 8; k++) {
        int t = (k << 8) + tid;
        atomicAdd(&hist[posv[b * NT + t]][posh[b * NT + t]], 1);
    }
    __syncthreads();
#pragma unroll
    for (int c = 0; c < 2; c++) {
        int cell = (c << 8) + tid;        // 512 cells: 64 j x 8 phl
        int j    = cell >> 3;
        int phl  = cell & 7;
        int ph   = (phg << 3) + phl;
        float s = 0.f;
        for (int k = 0; k < 64; k++)
            s += (float)hist[j][k] * g2s[63 + k - ph];
        tmp[j][phl] = s;
    }
    __syncthreads();
#pragma unroll
    for (int c = 0; c < 2; c++) {
        int cell = (c << 8) + tid;
        int pv   = cell >> 3;
        int phl  = cell & 7;
        int ph   = (phg << 3) + phl;
        float s = 0.f;
        for (int j = 0; j < 64; j++)
            s += g2s[63 + j - pv] * tmp[j][phl];
        invden[(b * 64 + pv) * 64 + ph] = 1.0f / s;
    }
}

// K2: h-conv from packed token lists.
//   B1[b][q][pv][d] = sum_{t: posv_t==pv} g(q - posh_t) * x[b][t][d]   (bf16 out)
// Block = (b, dc, pv-group of 4); wave w owns q-tile [16w,16w+16); lane owns d.
// Per token: 1 s_load (packed tok) + 1 coalesced x VMEM + 1 scalar 16-float
// g-window (s_load, correct choice here: 16 FRESH values per token) + 16 FMA.
// 8-deep token unroll keeps 8 x-loads in flight per wave.
__global__ __launch_bounds__(256) void k2_convh(
    const float* __restrict__ x,
    const int* __restrict__ tokv, const int* __restrict__ cntv,
    const float* __restrict__ G2f, ushort_t* __restrict__ B1, int b0)
{
    int pv0  = (blockIdx.x & 15) << 2;
    int dc   = (blockIdx.x >> 4) & 15;
    int b    = b0 + (blockIdx.x >> 8);
    int tid  = threadIdx.x;
    int lane = tid & 63;
    int goff = __builtin_amdgcn_readfirstlane(63 + ((tid >> 6) << 4));  // 63+16w
    int wq   = goff - 63;                                               // 16w
    int d0   = dc << 6;

    const float* xb = x + (((size_t)b * NT) << 10) + d0 + lane;

    for (int pvi = 0; pvi < 4; ++pvi) {
        int pv = pv0 + pvi;
        int n  = cntv[b * 64 + pv];
        const int* toks = tokv + ((size_t)(b * 64 + pv)) * CAP;

        float acc[16];
#pragma unroll
        for (int q = 0; q < 16; q++) acc[q] = 0.f;

        int i = 0;
        for (; i + 8 <= n; i += 8) {
            float xv[8]; const float* gp[8];
#pragma unroll
            for (int j = 0; j < 8; j++) {
                int pk = __builtin_amdgcn_readfirstlane(toks[i + j]);
                int t  = pk & 0xffff;
                int ph = pk >> 16;
                xv[j] = xb[(size_t)t << 10];
                gp[j] = G2f + (goff - ph);     // fully scalar address
            }
#pragma unroll
            for (int q = 0; q < 16; q++) {
                float a = acc[q];
#pragma unroll
                for (int j = 0; j < 8; j++)
                    a = fmaf(gp[j][q], xv[j], a);
                acc[q] = a;
            }
        }
        for (; i < n; i++) {
            int pk = __builtin_amdgcn_readfirstlane(toks[i]);
            int t  = pk & 0xffff;
            int ph = pk >> 16;
            float xv = xb[(size_t)t << 10];
            const float* gp = G2f + (goff - ph);
#pragma unroll
            for (int q = 0; q < 16; q++)
                acc[q] = fmaf(gp[q], xv, acc[q]);
        }

        // B1[b][q][pv][d] (bf16), q = wq + qi
        ushort_t* B1p = B1 + (((size_t)(b - b0)) << 22) + (((size_t)wq) << 16)
                      + (((size_t)pv) << 10) + d0 + lane;
#pragma unroll
        for (int q = 0; q < 16; q++)
            B1p[(size_t)q << 16] = f2bf(acc[q]);
    }
}

// K3: dense v-conv fused with token gather + normalization.
// ROUND-3 REGISTER PATTERN RESTORED: g window lives in VGPRs — per-lane
// loads (NOT readfirstlane'd: scalarizing pushed 79 values into a 64-SGPR
// budget -> in-loop s_load remat = the round-5 regression). Fully unrolled
// j-loop keeps all gv[] indices compile-time (no scratch).
// Stage u[j][d] = bf16 B1[b][ph][j][d] -> fp32 LDS; y = G*u; reuse u for y;
// scatter out[t][d] = y[pv_t][d] * invden[pv_t][ph] via packed token list.
__global__ __launch_bounds__(256) void k3_convv(
    const int* __restrict__ tokh, const int* __restrict__ cnth,
    const float* __restrict__ G2f, const ushort_t* __restrict__ B1,
    const float* __restrict__ invden, float* __restrict__ out, int b0)
{
    int ph   = blockIdx.x & 63;
    int dc   = (blockIdx.x >> 6) & 15;
    int b    = b0 + (blockIdx.x >> 10);
    int tid  = threadIdx.x;
    int lane = tid & 63;
    int w    = tid >> 6;
    int wq   = w << 4;                 // per-lane on purpose (VGPR g loads)
    int d0   = dc << 6;

    int n = cnth[b * 64 + ph];
    if (n == 0) return;               // uniform across block: safe

    __shared__ float u[64][64];       // staged B1 column; reused as y

    const ushort_t* B1p = B1 + (((size_t)(b - b0)) << 22) + (((size_t)ph) << 16)
                        + d0 + lane;
#pragma unroll
    for (int k = 0; k < 16; k++) {
        int j = (k << 2) + w;
        u[j][lane] = bf2f(B1p[(size_t)j << 10]);
    }

    // hoist the whole g window into VGPRs: conv needs g(wq+q-j) = G2f[wq+63+q-j],
    // (q,j) in [0,16)x[0,64) -> indices G2f[wq .. wq+78]
    float gv[79];
#pragma unroll
    for (int k = 0; k < 79; k++) gv[k] = G2f[wq + k];

    float acc[16];
#pragma unroll
    for (int q = 0; q < 16; q++) acc[q] = 0.f;

    __syncthreads();

#pragma unroll
    for (int j = 0; j < 64; j += 4) {
        float uv[4];
#pragma unroll
        for (int jj = 0; jj < 4; jj++) uv[jj] = u[j + jj][lane];
#pragma unroll
        for (int q = 0; q < 16; q++) {
            float a = acc[q];
#pragma unroll
            for (int jj = 0; jj < 4; jj++)
                a = fmaf(gv[63 + q - (j + jj)], uv[jj], a);
            acc[q] = a;
        }
    }
    __syncthreads();                   // all u reads complete
#pragma unroll
    for (int q = 0; q < 16; q++) u[wq + q][lane] = acc[q];   // y into u's LDS
    __syncthreads();

    const int* toks = tokh + ((size_t)(b * 64 + ph)) * CAP;
    float* outb = out + (((size_t)b * NT) << 10) + d0 + lane;
    const float* ivb = invden + ((b * 64) << 6) + ph;

    for (int i = w; i < n; i += 4) {
        int pk = __builtin_amdgcn_readfirstlane(toks[i]);
        int t  = pk & 0xffff;
        int pv = pk >> 16;
        float iv = ivb[pv << 6];       // uniform s_load
        outb[(size_t)t << 10] = u[pv][lane] * iv;
    }
}

// Safety-net fallback (no workspace needed): direct O(T^2 * D) attention.
__global__ __launch_bounds__(256) void k_naive(
    const float* __restrict__ x, const int* __restrict__ posv,
    const int* __restrict__ posh, float* __restrict__ out)
{
    int t   = blockIdx.x & (NT - 1);
    int b   = blockIdx.x >> 11;
    int tid = threadIdx.x;

    __shared__ float s_w[NT];
    __shared__ float s_red[256];

    int pvt = posv[b * NT + t];
    int pht = posh[b * NT + t];

    float dsum = 0.0f;
    for (int s = tid; s < NT; s += 256) {
        int dv = pvt - posv[b * NT + s];
        int dh = pht - posh[b * NT + s];
        float w = expf(-(float)(dv * dv + dh * dh) * (1.0f / 512.0f));
        s_w[s] = w;
        dsum += w;
    }
    s_red[tid] = dsum;
    __syncthreads();
    for (int off = 128; off > 0; off >>= 1) {
        if (tid < off) s_red[tid] += s_red[tid + off];
        __syncthreads();
    }
    float inv = 1.0f / s_red[0];

    float a0 = 0.f, a1 = 0.f, a2 = 0.f, a3 = 0.f;
    for (int s = 0; s < NT; s++) {
        float w = s_w[s];
        const float* xr = x + (((size_t)(b * NT + s)) << 10);
        a0 = fmaf(w, xr[tid + 0],   a0);
        a1 = fmaf(w, xr[tid + 256], a1);
        a2 = fmaf(w, xr[tid + 512], a2);
        a3 = fmaf(w, xr[tid + 768], a3);
    }
    size_t ob = (((size_t)(b * NT + t)) << 10) + tid;
    out[ob + 0]   = a0 * inv;
    out[ob + 256] = a1 * inv;
    out[ob + 512] = a2 * inv;
    out[ob + 768] = a3 * inv;
}

extern "C" void kernel_launch(void* const* d_in, const int* in_sizes, int n_in,
                              void* d_out, int out_size, void* d_ws, size_t ws_size,
                              hipStream_t stream) {
    const float* x    = (const float*)d_in[0];
    const int*   posv = (const int*)d_in[1];
    const int*   posh = (const int*)d_in[2];
    float*       out  = (float*)d_out;

    char* ws = (char*)d_ws;
    float*    gbase  = (float*)ws;               // pad + table
    float*    G2f    = (float*)(ws + OFF_G2);
    int*      cntv   = (int*)(ws + OFF_CNTV);
    int*      cnth   = (int*)(ws + OFF_CNTH);
    float*    invden = (float*)(ws + OFF_INVDEN);
    int*      tokv   = (int*)(ws + OFF_TOKV);
    int*      tokh   = (int*)(ws + OFF_TOKH);
    ushort_t* B1     = (ushort_t*)(ws + OFF_B1);

    const size_t needFull = (size_t)OFF_B1 + (size_t)NB * B1_SLAB;   // ~73 MB
    const size_t needLoop = (size_t)OFF_B1 + B1_SLAB;                // ~17 MB

    if (ws_size >= needFull) {
        k1_bucket<<<NB * 32, 256, 0, stream>>>(posv, posh, tokv, tokh, cntv, cnth, gbase);
        kden<<<NB * 8, 256, 0, stream>>>(posv, posh, G2f, invden, 0);
        k2_convh<<<NB * 256, 256, 0, stream>>>(x, tokv, cntv, G2f, B1, 0);
        k3_convv<<<NB * 1024, 256, 0, stream>>>(tokh, cnth, G2f, B1, invden, out, 0);
    } else if (ws_size >= needLoop) {
        k1_bucket<<<NB * 32, 256, 0, stream>>>(posv, posh, tokv, tokh, cntv, cnth, gbase);
        for (int b = 0; b < NB; b++) {
            kden<<<8, 256, 0, stream>>>(posv, posh, G2f, invden, b);
            k2_convh<<<256, 256, 0, stream>>>(x, tokv, cntv, G2f, B1, b);
            k3_convv<<<1024, 256, 0, stream>>>(tokh, cnth, G2f, B1, invden, out, b);
        }
    } else {
        k_naive<<<NB * NT, 256, 0, stream>>>(x, posv, posh, out);
    }
}

// Round 8
// 113.023 us; speedup vs baseline: 1.2239x; 1.0506x over previous
//
#include <hip/hip_runtime.h>
#include <hip/hip_bf16.h>

// Problem constants (fixed by setup_inputs): B=8, T=2048, D=1024, positions in [0,64).
#define NB 8
#define NT 2048
#define ND 1024
#define CAP 2048       // max tokens per bucket (worst case all T in one bucket)

typedef unsigned short ushort_t;

// bf16 helpers: store with RNE rounding (intrinsic), load via exact bit shift.
__device__ __forceinline__ ushort_t f2bf(float f) {
    __hip_bfloat16 h = __float2bfloat16(f);
    return *reinterpret_cast<ushort_t*>(&h);
}
__device__ __forceinline__ float bf2f(ushort_t u) {
    unsigned int v = ((unsigned int)u) << 16;
    return __int_as_float((int)v);
}

// ---------------------------------------------------------------------------
// Workspace layout (byte offsets):
//   pad    : 64 floats of zeros                                          @ 0
//   G2f    : 128 floats  g2[k] = exp(-(k-63)^2/512), valid k in [0,126]  @ 256
//   cntv   : NB*64 int                                                   @ 768
//   cnth   : NB*64 int                                                   @ 2816
//   invden : NB*64*64 float  1/denominator for a token at (pv,ph)        @ 4864
//   tokv   : NB*64*CAP int   packed (t | posh[t]<<16), bucketed by posv  @ 135936
//   tokh   : NB*64*CAP int   packed (t | posv[t]<<16), bucketed by posh  @ 4330240
//   B1     : NB*64*64*1024 bf16   [b][q=ph'][pv][d]                      @ 8524544
// ---------------------------------------------------------------------------
#define OFF_G2     256
#define OFF_CNTV   768
#define OFF_CNTH   2816
#define OFF_INVDEN 4864
#define OFF_TOKV   135936
#define OFF_TOKH   4330240
#define OFF_B1     8524544
#define B1_SLAB    ((size_t)64 * 64 * 1024 * 2)   // bytes per batch slab (8 MB, bf16)

// K1: deterministic CSR bucket lists via wave ballot compaction (no atomics).
// Entries packed: t | (other_axis_pos[t] << 16). Block 0 fills the g table.
__global__ __launch_bounds__(256) void k1_bucket(
    const int* __restrict__ posv, const int* __restrict__ posh,
    int* __restrict__ tokv, int* __restrict__ tokh,
    int* __restrict__ cntv, int* __restrict__ cnth,
    float* __restrict__ gbase)   // = ws base; table lives at gbase+64
{
    int b    = blockIdx.x >> 5;      // NB*32 blocks
    int blk  = blockIdx.x & 31;
    int wave = threadIdx.x >> 6;
    int lane = threadIdx.x & 63;

    if (blockIdx.x == 0 && threadIdx.x < 192) {
        int k = (int)threadIdx.x - 64;     // table index; <0 = pad
        float v = 0.0f;
        if (k >= 0 && k < 127) {
            int r = k - 63;
            v = expf(-(float)(r * r) * (1.0f / 512.0f));
        }
        gbase[threadIdx.x] = v;
    }

    int task   = blk * 4 + wave;                // 0..127
    int bucket = task & 63;
    int use_ph = task >> 6;
    const int* pos  = use_ph ? posh : posv;
    const int* opos = use_ph ? posv : posh;
    int* tok = (use_ph ? tokh : tokv) + ((size_t)(b * 64 + bucket)) * CAP;
    int* cnt = use_ph ? cnth : cntv;

    int vals[32];
#pragma unroll
    for (int k = 0; k < 32; k++) vals[k] = pos[b * NT + k * 64 + lane];

    unsigned long long lmask = (1ull << lane) - 1ull;
    int cursor = 0;
#pragma unroll 4
    for (int k = 0; k < 32; k++) {
        bool hit = (vals[k] == bucket);
        unsigned long long m = __ballot(hit);
        if (hit) {
            int t = k * 64 + lane;
            tok[cursor + __popcll(m & lmask)] = t | (opos[b * NT + t] << 16);
        }
        cursor += (int)__popcll(m);
    }
    if (lane == 0) cnt[b * 64 + bucket] = cursor;
}

// KDEN: denominator table. den[pv][ph] = sum_{j,k} hist[j][k] g(pv-j) g(ph-k).
// Integer LDS-atomic histogram (deterministic), then two 64x64 mini-matmuls.
__global__ __launch_bounds__(256) void kden(
    const int* __restrict__ posv, const int* __restrict__ posh,
    const float* __restrict__ G2f, float* __restrict__ invden, int b0)
{
    int b   = b0 + (blockIdx.x >> 3);
    int phg = blockIdx.x & 7;
    int tid = threadIdx.x;

    __shared__ int   hist[64][64];
    __shared__ float g2s[128];
    __shared__ float tmp[64][8];

#pragma unroll
    for (int k = 0; k < 16; k++) ((int*)hist)[tid + (k << 8)] = 0;
    if (tid < 128) g2s[tid] = G2f[tid];
    __syncthreads();
#pragma unroll
    for (int k = 0; k < 8; k++) {
        int t = (k << 8) + tid;
        atomicAdd(&hist[posv[b * NT + t]][posh[b * NT + t]], 1);
    }
    __syncthreads();
#pragma unroll
    for (int c = 0; c < 2; c++) {
        int cell = (c << 8) + tid;        // 512 cells: 64 j x 8 phl
        int j    = cell >> 3;
        int phl  = cell & 7;
        int ph   = (phg << 3) + phl;
        float s = 0.f;
        for (int k = 0; k < 64; k++)
            s += (float)hist[j][k] * g2s[63 + k - ph];
        tmp[j][phl] = s;
    }
    __syncthreads();
#pragma unroll
    for (int c = 0; c < 2; c++) {
        int cell = (c << 8) + tid;
        int pv   = cell >> 3;
        int phl  = cell & 7;
        int ph   = (phg << 3) + phl;
        float s = 0.f;
        for (int j = 0; j < 64; j++)
            s += g2s[63 + j - pv] * tmp[j][phl];
        invden[(b * 64 + pv) * 64 + ph] = 1.0f / s;
    }
}

// K2: h-conv from packed token lists.
//   B1[b][q][pv][d] = sum_{t: posv_t==pv} g(q - posh_t) * x[b][t][d]   (bf16 out)
// Block = (b, dc, pv-group of 4); wave w owns q-tile [16w,16w+16); lane owns d.
// Per token: 1 s_load (packed tok) + 1 coalesced x VMEM + 1 scalar 16-float
// g-window (s_load, correct choice here: 16 FRESH values per token) + 16 FMA.
__global__ __launch_bounds__(256) void k2_convh(
    const float* __restrict__ x,
    const int* __restrict__ tokv, const int* __restrict__ cntv,
    const float* __restrict__ G2f, ushort_t* __restrict__ B1, int b0)
{
    int pv0  = (blockIdx.x & 15) << 2;
    int dc   = (blockIdx.x >> 4) & 15;
    int b    = b0 + (blockIdx.x >> 8);
    int tid  = threadIdx.x;
    int lane = tid & 63;
    int goff = __builtin_amdgcn_readfirstlane(63 + ((tid >> 6) << 4));  // 63+16w
    int wq   = goff - 63;                                               // 16w
    int d0   = dc << 6;

    const float* xb = x + (((size_t)b * NT) << 10) + d0 + lane;

    for (int pvi = 0; pvi < 4; ++pvi) {
        int pv = pv0 + pvi;
        int n  = cntv[b * 64 + pv];
        const int* toks = tokv + ((size_t)(b * 64 + pv)) * CAP;

        float acc[16];
#pragma unroll
        for (int q = 0; q < 16; q++) acc[q] = 0.f;

        int i = 0;
        for (; i + 8 <= n; i += 8) {
            float xv[8]; const float* gp[8];
#pragma unroll
            for (int j = 0; j < 8; j++) {
                int pk = __builtin_amdgcn_readfirstlane(toks[i + j]);
                int t  = pk & 0xffff;
                int ph = pk >> 16;
                xv[j] = xb[(size_t)t << 10];
                gp[j] = G2f + (goff - ph);     // fully scalar address
            }
#pragma unroll
            for (int q = 0; q < 16; q++) {
                float a = acc[q];
#pragma unroll
                for (int j = 0; j < 8; j++)
                    a = fmaf(gp[j][q], xv[j], a);
                acc[q] = a;
            }
        }
        for (; i < n; i++) {
            int pk = __builtin_amdgcn_readfirstlane(toks[i]);
            int t  = pk & 0xffff;
            int ph = pk >> 16;
            float xv = xb[(size_t)t << 10];
            const float* gp = G2f + (goff - ph);
#pragma unroll
            for (int q = 0; q < 16; q++)
                acc[q] = fmaf(gp[q], xv, acc[q]);
        }

        // B1[b][q][pv][d] (bf16), q = wq + qi
        ushort_t* B1p = B1 + (((size_t)(b - b0)) << 22) + (((size_t)wq) << 16)
                      + (((size_t)pv) << 10) + d0 + lane;
#pragma unroll
        for (int q = 0; q < 16; q++)
            B1p[(size_t)q << 16] = f2bf(acc[q]);
    }
}

// K3: dense v-conv fused with token gather + normalization.
// __launch_bounds__(256, 1): the round-7 fix. The conv needs the 79-value
// g-window + acc[16] live (~110 VGPR). At default occupancy targets the
// allocator capped at 56 VGPR and spilled the window to AGPRs
// (v_accvgpr_read/write = VALU) -> the measured 2.3x VALU-cycle inflation.
// min-waves=1 lifts the budget to 512; ~110 VGPR still gives 4 waves/SIMD.
// g loads are written at their use (per-lane pointer, NOT readfirstlane'd:
// scalarizing = round-5 regression, 79 values don't fit SGPR budget);
// full unroll makes them loop-invariant -> LICM hoists into VGPRs.
__global__ __launch_bounds__(256, 1) void k3_convv(
    const int* __restrict__ tokh, const int* __restrict__ cnth,
    const float* __restrict__ G2f, const ushort_t* __restrict__ B1,
    const float* __restrict__ invden, float* __restrict__ out, int b0)
{
    int ph   = blockIdx.x & 63;
    int dc   = (blockIdx.x >> 6) & 15;
    int b    = b0 + (blockIdx.x >> 10);
    int tid  = threadIdx.x;
    int lane = tid & 63;
    int w    = tid >> 6;
    int wq   = w << 4;                 // per-lane on purpose (VGPR g loads)
    int d0   = dc << 6;

    int n = cnth[b * 64 + ph];
    if (n == 0) return;               // uniform across block: safe

    __shared__ float u[64][64];       // staged B1 column; reused as y

    const ushort_t* B1p = B1 + (((size_t)(b - b0)) << 22) + (((size_t)ph) << 16)
                        + d0 + lane;
#pragma unroll
    for (int k = 0; k < 16; k++) {
        int j = (k << 2) + w;
        u[j][lane] = bf2f(B1p[(size_t)j << 10]);
    }

    const float* gq = G2f + 63 + wq;   // conv window: gq[-63 .. +15]

    float acc[16];
#pragma unroll
    for (int q = 0; q < 16; q++) acc[q] = 0.f;

    __syncthreads();

#pragma unroll
    for (int j = 0; j < 64; j += 4) {
        float uv[4];
#pragma unroll
        for (int jj = 0; jj < 4; jj++) uv[jj] = u[j + jj][lane];
#pragma unroll
        for (int q = 0; q < 16; q++) {
            float a = acc[q];
#pragma unroll
            for (int jj = 0; jj < 4; jj++)
                a = fmaf(gq[q - (j + jj)], uv[jj], a);
            acc[q] = a;
        }
    }
    __syncthreads();                   // all u reads complete
#pragma unroll
    for (int q = 0; q < 16; q++) u[wq + q][lane] = acc[q];   // y into u's LDS
    __syncthreads();

    const int* toks = tokh + ((size_t)(b * 64 + ph)) * CAP;
    float* outb = out + (((size_t)b * NT) << 10) + d0 + lane;
    const float* ivb = invden + ((b * 64) << 6) + ph;

    for (int i = w; i < n; i += 4) {
        int pk = __builtin_amdgcn_readfirstlane(toks[i]);
        int t  = pk & 0xffff;
        int pv = pk >> 16;
        float iv = ivb[pv << 6];       // uniform s_load
        outb[(size_t)t << 10] = u[pv][lane] * iv;
    }
}

// Safety-net fallback (no workspace needed): direct O(T^2 * D) attention.
__global__ __launch_bounds__(256) void k_naive(
    const float* __restrict__ x, const int* __restrict__ posv,
    const int* __restrict__ posh, float* __restrict__ out)
{
    int t   = blockIdx.x & (NT - 1);
    int b   = blockIdx.x >> 11;
    int tid = threadIdx.x;

    __shared__ float s_w[NT];
    __shared__ float s_red[256];

    int pvt = posv[b * NT + t];
    int pht = posh[b * NT + t];

    float dsum = 0.0f;
    for (int s = tid; s < NT; s += 256) {
        int dv = pvt - posv[b * NT + s];
        int dh = pht - posh[b * NT + s];
        float w = expf(-(float)(dv * dv + dh * dh) * (1.0f / 512.0f));
        s_w[s] = w;
        dsum += w;
    }
    s_red[tid] = dsum;
    __syncthreads();
    for (int off = 128; off > 0; off >>= 1) {
        if (tid < off) s_red[tid] += s_red[tid + off];
        __syncthreads();
    }
    float inv = 1.0f / s_red[0];

    float a0 = 0.f, a1 = 0.f, a2 = 0.f, a3 = 0.f;
    for (int s = 0; s < NT; s++) {
        float w = s_w[s];
        const float* xr = x + (((size_t)(b * NT + s)) << 10);
        a0 = fmaf(w, xr[tid + 0],   a0);
        a1 = fmaf(w, xr[tid + 256], a1);
        a2 = fmaf(w, xr[tid + 512], a2);
        a3 = fmaf(w, xr[tid + 768], a3);
    }
    size_t ob = (((size_t)(b * NT + t)) << 10) + tid;
    out[ob + 0]   = a0 * inv;
    out[ob + 256] = a1 * inv;
    out[ob + 512] = a2 * inv;
    out[ob + 768] = a3 * inv;
}

extern "C" void kernel_launch(void* const* d_in, const int* in_sizes, int n_in,
                              void* d_out, int out_size, void* d_ws, size_t ws_size,
                              hipStream_t stream) {
    const float* x    = (const float*)d_in[0];
    const int*   posv = (const int*)d_in[1];
    const int*   posh = (const int*)d_in[2];
    float*       out  = (float*)d_out;

    char* ws = (char*)d_ws;
    float*    gbase  = (float*)ws;               // pad + table
    float*    G2f    = (float*)(ws + OFF_G2);
    int*      cntv   = (int*)(ws + OFF_CNTV);
    int*      cnth   = (int*)(ws + OFF_CNTH);
    float*    invden = (float*)(ws + OFF_INVDEN);
    int*      tokv   = (int*)(ws + OFF_TOKV);
    int*      tokh   = (int*)(ws + OFF_TOKH);
    ushort_t* B1     = (ushort_t*)(ws + OFF_B1);

    const size_t needFull = (size_t)OFF_B1 + (size_t)NB * B1_SLAB;   // ~73 MB
    const size_t needLoop = (size_t)OFF_B1 + B1_SLAB;                // ~17 MB

    if (ws_size >= needFull) {
        k1_bucket<<<NB * 32, 256, 0, stream>>>(posv, posh, tokv, tokh, cntv, cnth, gbase);
        kden<<<NB * 8, 256, 0, stream>>>(posv, posh, G2f, invden, 0);
        k2_convh<<<NB * 256, 256, 0, stream>>>(x, tokv, cntv, G2f, B1, 0);
        k3_convv<<<NB * 1024, 256, 0, stream>>>(tokh, cnth, G2f, B1, invden, out, 0);
    } else if (ws_size >= needLoop) {
        k1_bucket<<<NB * 32, 256, 0, stream>>>(posv, posh, tokv, tokh, cntv, cnth, gbase);
        for (int b = 0; b < NB; b++) {
            kden<<<8, 256, 0, stream>>>(posv, posh, G2f, invden, b);
            k2_convh<<<256, 256, 0, stream>>>(x, tokv, cntv, G2f, B1, b);
            k3_convv<<<1024, 256, 0, stream>>>(tokh, cnth, G2f, B1, invden, out, b);
        }
    } else {
        k_naive<<<NB * NT, 256, 0, stream>>>(x, posv, posh, out);
    }
}

// Round 9
// 106.146 us; speedup vs baseline: 1.3032x; 1.0648x over previous
//
#include <hip/hip_runtime.h>
#include <hip/hip_bf16.h>

// Problem constants (fixed by setup_inputs): B=8, T=2048, D=1024, positions in [0,64).
#define NB 8
#define NT 2048
#define ND 1024
#define CAP 2048       // max tokens per bucket (worst case all T in one bucket)

typedef unsigned short ushort_t;

// bf16 helpers: store with RNE rounding (intrinsic), load via exact bit shift.
__device__ __forceinline__ ushort_t f2bf(float f) {
    __hip_bfloat16 h = __float2bfloat16(f);
    return *reinterpret_cast<ushort_t*>(&h);
}
__device__ __forceinline__ float bf2f(ushort_t u) {
    unsigned int v = ((unsigned int)u) << 16;
    return __int_as_float((int)v);
}

// ---------------------------------------------------------------------------
// Workspace layout (byte offsets):
//   pad    : 64 floats of zeros                                          @ 0
//   G2f    : 128 floats  g2[k] = exp(-(k-63)^2/512), valid k in [0,126]  @ 256
//   cntv   : NB*64 int                                                   @ 768
//   cnth   : NB*64 int                                                   @ 2816
//   invden : NB*64*64 float  1/denominator for a token at (pv,ph)        @ 4864
//   tokv   : NB*64*CAP int   packed (t | posh[t]<<16), bucketed by posv  @ 135936
//   tokh   : NB*64*CAP int   packed (t | posv[t]<<16), bucketed by posh  @ 4330240
//   B1     : NB*64*64*1024 bf16   [b][q=ph'][pv][d]                      @ 8524544
// ---------------------------------------------------------------------------
#define OFF_G2     256
#define OFF_CNTV   768
#define OFF_CNTH   2816
#define OFF_INVDEN 4864
#define OFF_TOKV   135936
#define OFF_TOKH   4330240
#define OFF_B1     8524544
#define B1_SLAB    ((size_t)64 * 64 * 1024 * 2)   // bytes per batch slab (8 MB, bf16)

// K1: deterministic CSR bucket lists via wave ballot compaction (no atomics).
// Entries packed: t | (other_axis_pos[t] << 16). Block 0 fills the g table.
__global__ __launch_bounds__(256) void k1_bucket(
    const int* __restrict__ posv, const int* __restrict__ posh,
    int* __restrict__ tokv, int* __restrict__ tokh,
    int* __restrict__ cntv, int* __restrict__ cnth,
    float* __restrict__ gbase)   // = ws base; table lives at gbase+64
{
    int b    = blockIdx.x >> 5;      // NB*32 blocks
    int blk  = blockIdx.x & 31;
    int wave = threadIdx.x >> 6;
    int lane = threadIdx.x & 63;

    if (blockIdx.x == 0 && threadIdx.x < 192) {
        int k = (int)threadIdx.x - 64;     // table index; <0 = pad
        float v = 0.0f;
        if (k >= 0 && k < 127) {
            int r = k - 63;
            v = expf(-(float)(r * r) * (1.0f / 512.0f));
        }
        gbase[threadIdx.x] = v;
    }

    int task   = blk * 4 + wave;                // 0..127
    int bucket = task & 63;
    int use_ph = task >> 6;
    const int* pos  = use_ph ? posh : posv;
    const int* opos = use_ph ? posv : posh;
    int* tok = (use_ph ? tokh : tokv) + ((size_t)(b * 64 + bucket)) * CAP;
    int* cnt = use_ph ? cnth : cntv;

    int vals[32];
#pragma unroll
    for (int k = 0; k < 32; k++) vals[k] = pos[b * NT + k * 64 + lane];

    unsigned long long lmask = (1ull << lane) - 1ull;
    int cursor = 0;
#pragma unroll 4
    for (int k = 0; k < 32; k++) {
        bool hit = (vals[k] == bucket);
        unsigned long long m = __ballot(hit);
        if (hit) {
            int t = k * 64 + lane;
            tok[cursor + __popcll(m & lmask)] = t | (opos[b * NT + t] << 16);
        }
        cursor += (int)__popcll(m);
    }
    if (lane == 0) cnt[b * 64 + bucket] = cursor;
}

// KDEN: denominator table. den[pv][ph] = sum_{j,k} hist[j][k] g(pv-j) g(ph-k).
// Integer LDS-atomic histogram (deterministic), then two 64x64 mini-matmuls.
__global__ __launch_bounds__(256) void kden(
    const int* __restrict__ posv, const int* __restrict__ posh,
    const float* __restrict__ G2f, float* __restrict__ invden, int b0)
{
    int b   = b0 + (blockIdx.x >> 3);
    int phg = blockIdx.x & 7;
    int tid = threadIdx.x;

    __shared__ int   hist[64][64];
    __shared__ float g2s[128];
    __shared__ float tmp[64][8];

#pragma unroll
    for (int k = 0; k < 16; k++) ((int*)hist)[tid + (k << 8)] = 0;
    if (tid < 128) g2s[tid] = G2f[tid];
    __syncthreads();
#pragma unroll
    for (int k = 0; k < 8; k++) {
        int t = (k << 8) + tid;
        atomicAdd(&hist[posv[b * NT + t]][posh[b * NT + t]], 1);
    }
    __syncthreads();
#pragma unroll
    for (int c = 0; c < 2; c++) {
        int cell = (c << 8) + tid;        // 512 cells: 64 j x 8 phl
        int j    = cell >> 3;
        int phl  = cell & 7;
        int ph   = (phg << 3) + phl;
        float s = 0.f;
        for (int k = 0; k < 64; k++)
            s += (float)hist[j][k] * g2s[63 + k - ph];
        tmp[j][phl] = s;
    }
    __syncthreads();
#pragma unroll
    for (int c = 0; c < 2; c++) {
        int cell = (c << 8) + tid;
        int pv   = cell >> 3;
        int phl  = cell & 7;
        int ph   = (phg << 3) + phl;
        float s = 0.f;
        for (int j = 0; j < 64; j++)
            s += g2s[63 + j - pv] * tmp[j][phl];
        invden[(b * 64 + pv) * 64 + ph] = 1.0f / s;
    }
}

// K2: h-conv from packed token lists, 4-wide in d per lane.
//   B1[b][q][pv][d] = sum_{t: posv_t==pv} g(q - posh_t) * x[b][t][d]   (bf16 out)
// Block = (b, dc of 256 d, pv); wave w owns q-tile [16w,16w+16); lane owns
// 4 consecutive d (float4 x-gather = 1KB/wave). Per token per wave: 1 toks
// s_load + 1 scalar g-window + 1 VMEM + 64 FMA — 4x the FMA per dependent
// chain vs round 8 (which stalled 70%: VALUBusy 29%, the chain replicated
// across 16 dc blocks). acc[16][4]+xv[8][4] ~ 110 VGPR -> launch_bounds(,1)
// (round-7 lesson: default budget spills to AGPR = VALU-inflating movs).
__global__ __launch_bounds__(256, 1) void k2_convh(
    const float* __restrict__ x,
    const int* __restrict__ tokv, const int* __restrict__ cntv,
    const float* __restrict__ G2f, ushort_t* __restrict__ B1, int b0)
{
    int pv   = blockIdx.x & 63;
    int dc   = (blockIdx.x >> 6) & 3;
    int b    = b0 + (blockIdx.x >> 8);
    int tid  = threadIdx.x;
    int lane = tid & 63;
    int goff = __builtin_amdgcn_readfirstlane(63 + ((tid >> 6) << 4));  // 63+16w
    int wq   = goff - 63;                                               // 16w
    int d0   = (dc << 8) + (lane << 2);   // this lane's 4 d values

    const float4* xb = (const float4*)(x + (((size_t)b * NT) << 10) + d0);
    // xb[t << 8] = x[b][t][d0 .. d0+4)

    int n = cntv[b * 64 + pv];
    const int* toks = tokv + ((size_t)(b * 64 + pv)) * CAP;

    float acc[16][4];
#pragma unroll
    for (int q = 0; q < 16; q++)
#pragma unroll
        for (int c = 0; c < 4; c++) acc[q][c] = 0.f;

    int i = 0;
    for (; i + 8 <= n; i += 8) {
        float4 xv[8]; const float* gp[8];
#pragma unroll
        for (int j = 0; j < 8; j++) {
            int pk = __builtin_amdgcn_readfirstlane(toks[i + j]);
            int t  = pk & 0xffff;
            int ph = pk >> 16;
            xv[j] = xb[(size_t)t << 8];
            gp[j] = G2f + (goff - ph);     // fully scalar address
        }
#pragma unroll
        for (int q = 0; q < 16; q++) {
#pragma unroll
            for (int j = 0; j < 8; j++) {
                float g = gp[j][q];
                acc[q][0] = fmaf(g, xv[j].x, acc[q][0]);
                acc[q][1] = fmaf(g, xv[j].y, acc[q][1]);
                acc[q][2] = fmaf(g, xv[j].z, acc[q][2]);
                acc[q][3] = fmaf(g, xv[j].w, acc[q][3]);
            }
        }
    }
    for (; i < n; i++) {
        int pk = __builtin_amdgcn_readfirstlane(toks[i]);
        int t  = pk & 0xffff;
        int ph = pk >> 16;
        float4 xv = xb[(size_t)t << 8];
        const float* gp = G2f + (goff - ph);
#pragma unroll
        for (int q = 0; q < 16; q++) {
            float g = gp[q];
            acc[q][0] = fmaf(g, xv.x, acc[q][0]);
            acc[q][1] = fmaf(g, xv.y, acc[q][1]);
            acc[q][2] = fmaf(g, xv.z, acc[q][2]);
            acc[q][3] = fmaf(g, xv.w, acc[q][3]);
        }
    }

    // B1[b][q][pv][d] (bf16), q = wq + qi; 4 bf16 packed as uint2 per store
    ushort_t* B1p = B1 + (((size_t)(b - b0)) << 22) + (((size_t)wq) << 16)
                  + (((size_t)pv) << 10) + d0;
#pragma unroll
    for (int q = 0; q < 16; q++) {
        uint2 s;
        s.x = (unsigned int)f2bf(acc[q][0]) | ((unsigned int)f2bf(acc[q][1]) << 16);
        s.y = (unsigned int)f2bf(acc[q][2]) | ((unsigned int)f2bf(acc[q][3]) << 16);
        *reinterpret_cast<uint2*>(B1p + ((size_t)q << 16)) = s;
    }
}

// K3: dense v-conv fused with token gather + normalization.
// __launch_bounds__(256, 1): allocator budget for the hoisted 79-value
// g-window + acc[16] (~110 VGPR); default budget spilled to AGPRs (round 7).
// g loads per-lane (NOT readfirstlane'd: 79 values overflow SGPRs, round-5
// regression); full unroll -> LICM hoists them into VGPRs once.
__global__ __launch_bounds__(256, 1) void k3_convv(
    const int* __restrict__ tokh, const int* __restrict__ cnth,
    const float* __restrict__ G2f, const ushort_t* __restrict__ B1,
    const float* __restrict__ invden, float* __restrict__ out, int b0)
{
    int ph   = blockIdx.x & 63;
    int dc   = (blockIdx.x >> 6) & 15;
    int b    = b0 + (blockIdx.x >> 10);
    int tid  = threadIdx.x;
    int lane = tid & 63;
    int w    = tid >> 6;
    int wq   = w << 4;                 // per-lane on purpose (VGPR g loads)
    int d0   = dc << 6;

    int n = cnth[b * 64 + ph];
    if (n == 0) return;               // uniform across block: safe

    __shared__ float u[64][64];       // staged B1 column; reused as y

    const ushort_t* B1p = B1 + (((size_t)(b - b0)) << 22) + (((size_t)ph) << 16)
                        + d0 + lane;
#pragma unroll
    for (int k = 0; k < 16; k++) {
        int j = (k << 2) + w;
        u[j][lane] = bf2f(B1p[(size_t)j << 10]);
    }

    const float* gq = G2f + 63 + wq;   // conv window: gq[-63 .. +15]

    float acc[16];
#pragma unroll
    for (int q = 0; q < 16; q++) acc[q] = 0.f;

    __syncthreads();

#pragma unroll
    for (int j = 0; j < 64; j += 4) {
        float uv[4];
#pragma unroll
        for (int jj = 0; jj < 4; jj++) uv[jj] = u[j + jj][lane];
#pragma unroll
        for (int q = 0; q < 16; q++) {
            float a = acc[q];
#pragma unroll
            for (int jj = 0; jj < 4; jj++)
                a = fmaf(gq[q - (j + jj)], uv[jj], a);
            acc[q] = a;
        }
    }
    __syncthreads();                   // all u reads complete
#pragma unroll
    for (int q = 0; q < 16; q++) u[wq + q][lane] = acc[q];   // y into u's LDS
    __syncthreads();

    const int* toks = tokh + ((size_t)(b * 64 + ph)) * CAP;
    float* outb = out + (((size_t)b * NT) << 10) + d0 + lane;
    const float* ivb = invden + ((b * 64) << 6) + ph;

    for (int i = w; i < n; i += 4) {
        int pk = __builtin_amdgcn_readfirstlane(toks[i]);
        int t  = pk & 0xffff;
        int pv = pk >> 16;
        float iv = ivb[pv << 6];       // uniform s_load
        outb[(size_t)t << 10] = u[pv][lane] * iv;
    }
}

// Safety-net fallback (no workspace needed): direct O(T^2 * D) attention.
__global__ __launch_bounds__(256) void k_naive(
    const float* __restrict__ x, const int* __restrict__ posv,
    const int* __restrict__ posh, float* __restrict__ out)
{
    int t   = blockIdx.x & (NT - 1);
    int b   = blockIdx.x >> 11;
    int tid = threadIdx.x;

    __shared__ float s_w[NT];
    __shared__ float s_red[256];

    int pvt = posv[b * NT + t];
    int pht = posh[b * NT + t];

    float dsum = 0.0f;
    for (int s = tid; s < NT; s += 256) {
        int dv = pvt - posv[b * NT + s];
        int dh = pht - posh[b * NT + s];
        float w = expf(-(float)(dv * dv + dh * dh) * (1.0f / 512.0f));
        s_w[s] = w;
        dsum += w;
    }
    s_red[tid] = dsum;
    __syncthreads();
    for (int off = 128; off > 0; off >>= 1) {
        if (tid < off) s_red[tid] += s_red[tid + off];
        __syncthreads();
    }
    float inv = 1.0f / s_red[0];

    float a0 = 0.f, a1 = 0.f, a2 = 0.f, a3 = 0.f;
    for (int s = 0; s < NT; s++) {
        float w = s_w[s];
        const float* xr = x + (((size_t)(b * NT + s)) << 10);
        a0 = fmaf(w, xr[tid + 0],   a0);
        a1 = fmaf(w, xr[tid + 256], a1);
        a2 = fmaf(w, xr[tid + 512], a2);
        a3 = fmaf(w, xr[tid + 768], a3);
    }
    size_t ob = (((size_t)(b * NT + t)) << 10) + tid;
    out[ob + 0]   = a0 * inv;
    out[ob + 256] = a1 * inv;
    out[ob + 512] = a2 * inv;
    out[ob + 768] = a3 * inv;
}

extern "C" void kernel_launch(void* const* d_in, const int* in_sizes, int n_in,
                              void* d_out, int out_size, void* d_ws, size_t ws_size,
                              hipStream_t stream) {
    const float* x    = (const float*)d_in[0];
    const int*   posv = (const int*)d_in[1];
    const int*   posh = (const int*)d_in[2];
    float*       out  = (float*)d_out;

    char* ws = (char*)d_ws;
    float*    gbase  = (float*)ws;               // pad + table
    float*    G2f    = (float*)(ws + OFF_G2);
    int*      cntv   = (int*)(ws + OFF_CNTV);
    int*      cnth   = (int*)(ws + OFF_CNTH);
    float*    invden = (float*)(ws + OFF_INVDEN);
    int*      tokv   = (int*)(ws + OFF_TOKV);
    int*      tokh   = (int*)(ws + OFF_TOKH);
    ushort_t* B1     = (ushort_t*)(ws + OFF_B1);

    const size_t needFull = (size_t)OFF_B1 + (size_t)NB * B1_SLAB;   // ~73 MB
    const size_t needLoop = (size_t)OFF_B1 + B1_SLAB;                // ~17 MB

    if (ws_size >= needFull) {
        k1_bucket<<<NB * 32, 256, 0, stream>>>(posv, posh, tokv, tokh, cntv, cnth, gbase);
        kden<<<NB * 8, 256, 0, stream>>>(posv, posh, G2f, invden, 0);
        k2_convh<<<NB * 256, 256, 0, stream>>>(x, tokv, cntv, G2f, B1, 0);
        k3_convv<<<NB * 1024, 256, 0, stream>>>(tokh, cnth, G2f, B1, invden, out, 0);
    } else if (ws_size >= needLoop) {
        k1_bucket<<<NB * 32, 256, 0, stream>>>(posv, posh, tokv, tokh, cntv, cnth, gbase);
        for (int b = 0; b < NB; b++) {
            kden<<<8, 256, 0, stream>>>(posv, posh, G2f, invden, b);
            k2_convh<<<256, 256, 0, stream>>>(x, tokv, cntv, G2f, B1, b);
            k3_convv<<<1024, 256, 0, stream>>>(tokh, cnth, G2f, B1, invden, out, b);
        }
    } else {
        k_naive<<<NB * NT, 256, 0, stream>>>(x, posv, posh, out);
    }
}